// Round 1
// baseline (638.152 us; speedup 1.0000x reference)
//
#include <hip/hip_runtime.h>
#include <cstdint>
#include <cstddef>

#define FD 128
#define CO 64

// ---------------- CSR build ----------------

__global__ __launch_bounds__(256) void k_deg(const int* __restrict__ src,
                                             const int* __restrict__ dst,
                                             int* __restrict__ deg_out,
                                             int* __restrict__ deg_in, int E) {
  int e = blockIdx.x * 256 + threadIdx.x;
  if (e < E) {
    atomicAdd(&deg_out[src[e]], 1);
    atomicAdd(&deg_in[dst[e]], 1);
  }
}

__global__ __launch_bounds__(256) void k_norm(const int* __restrict__ deg_out,
                                              const int* __restrict__ deg_in,
                                              float* __restrict__ d_src,
                                              float* __restrict__ d_dst, int N) {
  int i = blockIdx.x * 256 + threadIdx.x;
  if (i < N) {
    int a = deg_out[i];
    int b = deg_in[i];
    d_src[i] = rsqrtf((float)(a > 0 ? a : 1));
    d_dst[i] = rsqrtf((float)(b > 0 ? b : 1));
  }
}

// exclusive scan of deg_in into row_ptr (single block, chunked)
__global__ __launch_bounds__(1024) void k_scan(const int* __restrict__ deg_in,
                                               int* __restrict__ row_ptr, int N) {
  __shared__ int sums[1024];
  int tid = threadIdx.x;
  int CH = (N + 1023) >> 10;
  int start = tid * CH;
  int s = 0;
  for (int i = 0; i < CH; i++) {
    int idx = start + i;
    if (idx < N) s += deg_in[idx];
  }
  sums[tid] = s;
  __syncthreads();
  for (int off = 1; off < 1024; off <<= 1) {
    int v = (tid >= off) ? sums[tid - off] : 0;
    __syncthreads();
    sums[tid] += v;
    __syncthreads();
  }
  int run = (tid == 0) ? 0 : sums[tid - 1];
  for (int i = 0; i < CH; i++) {
    int idx = start + i;
    if (idx < N) {
      row_ptr[idx] = run;
      run += deg_in[idx];
    }
  }
  if (tid == 1023) row_ptr[N] = run;
}

__global__ __launch_bounds__(256) void k_fill(const int* __restrict__ src,
                                              const int* __restrict__ dst,
                                              const int* __restrict__ row_ptr,
                                              int* __restrict__ cursor,
                                              int* __restrict__ esrc, int E) {
  int e = blockIdx.x * 256 + threadIdx.x;
  if (e < E) {
    int d = dst[e];
    int pos = row_ptr[d] + atomicAdd(&cursor[d], 1);
    esrc[pos] = src[e];
  }
}

// ---------------- GEMM: out[N][NCW] = (A (*dsc rows)) @ W (+ bias) ----------------
// tile: 64 rows x 64 cols per block; grid.y selects the 64-col slice.

template <int NCW, bool SCALE, bool BIAS>
__global__ __launch_bounds__(256) void k_gemm(const float* __restrict__ A,
                                              const float* __restrict__ W,
                                              const float* __restrict__ bias,
                                              const float* __restrict__ dsc,
                                              float* __restrict__ out, int N) {
  __shared__ float Alds[64][FD + 4];   // +4 pad keeps float4 alignment, breaks bank aliasing
  __shared__ float Wlds[FD][64];
  int tid = threadIdx.x;
  int rowBase = blockIdx.x * 64;
  int colBase = blockIdx.y * 64;

  // load W tile [128][64] as float4
  for (int i = tid; i < FD * 16; i += 256) {
    int r = i >> 4, c4 = i & 15;
    float4 w = *(const float4*)(W + (size_t)r * NCW + colBase + c4 * 4);
    *(float4*)(&Wlds[r][c4 * 4]) = w;
  }
  // load A tile [64][128] as float4 (optionally row-scaled)
  for (int i = tid; i < 64 * 32; i += 256) {
    int r = i >> 5, c4 = i & 31;
    int gr = rowBase + r;
    float4 a = make_float4(0.f, 0.f, 0.f, 0.f);
    if (gr < N) {
      a = *(const float4*)(A + (size_t)gr * FD + c4 * 4);
      if (SCALE) {
        float s = dsc[gr];
        a.x *= s; a.y *= s; a.z *= s; a.w *= s;
      }
    }
    *(float4*)(&Alds[r][c4 * 4]) = a;
  }
  __syncthreads();

  int tx = tid & 15, ty = tid >> 4;
  int c0 = tx * 4, r0 = ty * 4;
  float acc[4][4] = {{0.f}};

#pragma unroll 8
  for (int k = 0; k < FD; k++) {
    float4 w = *(const float4*)(&Wlds[k][c0]);
    float a0 = Alds[r0 + 0][k];
    float a1 = Alds[r0 + 1][k];
    float a2 = Alds[r0 + 2][k];
    float a3 = Alds[r0 + 3][k];
    acc[0][0] += a0 * w.x; acc[0][1] += a0 * w.y; acc[0][2] += a0 * w.z; acc[0][3] += a0 * w.w;
    acc[1][0] += a1 * w.x; acc[1][1] += a1 * w.y; acc[1][2] += a1 * w.z; acc[1][3] += a1 * w.w;
    acc[2][0] += a2 * w.x; acc[2][1] += a2 * w.y; acc[2][2] += a2 * w.z; acc[2][3] += a2 * w.w;
    acc[3][0] += a3 * w.x; acc[3][1] += a3 * w.y; acc[3][2] += a3 * w.z; acc[3][3] += a3 * w.w;
  }

  float4 bv = make_float4(0.f, 0.f, 0.f, 0.f);
  if (BIAS) bv = *(const float4*)(bias + colBase + c0);
#pragma unroll
  for (int i = 0; i < 4; i++) {
    int gr = rowBase + r0 + i;
    if (gr < N) {
      float4 o;
      o.x = acc[i][0] + bv.x;
      o.y = acc[i][1] + bv.y;
      o.z = acc[i][2] + bv.z;
      o.w = acc[i][3] + bv.w;
      *(float4*)(out + (size_t)gr * NCW + colBase + c0) = o;
    }
  }
}

// ---------------- Aggregation: out[n] = f(sum_{e in CSR row n} h[esrc[e]]) ----------------
// one wave (64 lanes) per node, float2 per lane covers 128 features.

template <bool RELU, bool RES>
__global__ __launch_bounds__(256) void k_agg(const float* __restrict__ h,
                                             const int* __restrict__ row_ptr,
                                             const int* __restrict__ esrc,
                                             const float* __restrict__ d_dst,
                                             const float* __restrict__ bias,
                                             const float* __restrict__ res,
                                             float* __restrict__ out, int N) {
  int node = blockIdx.x * 4 + (threadIdx.x >> 6);
  int lane = threadIdx.x & 63;
  if (node >= N) return;
  int beg = row_ptr[node], end = row_ptr[node + 1];
  const float2* h2 = (const float2*)h;
  float ax = 0.f, ay = 0.f;
  for (int e = beg; e < end; e++) {
    int s = esrc[e];
    float2 v = h2[(size_t)s * 64 + lane];
    ax += v.x;
    ay += v.y;
  }
  float d = d_dst[node];
  float2 b = ((const float2*)bias)[lane];
  float vx = ax * d + b.x;
  float vy = ay * d + b.y;
  if (RES) {
    float2 r = ((const float2*)res)[(size_t)node * 64 + lane];
    vx += r.x;
    vy += r.y;
  }
  if (RELU) {
    vx = fmaxf(vx, 0.f);
    vy = fmaxf(vy, 0.f);
  }
  float2 o;
  o.x = vx;
  o.y = vy;
  ((float2*)out)[(size_t)node * 64 + lane] = o;
}

// ---------------- launch ----------------

extern "C" void kernel_launch(void* const* d_in, const int* in_sizes, int n_in,
                              void* d_out, int out_size, void* d_ws, size_t ws_size,
                              hipStream_t stream) {
  (void)n_in; (void)out_size; (void)ws_size;
  const float* x  = (const float*)d_in[0];
  const int*   src = (const int*)d_in[1];
  const int*   dst = (const int*)d_in[2];
  const float* W1 = (const float*)d_in[3];
  const float* b1 = (const float*)d_in[4];
  const float* W2 = (const float*)d_in[5];
  const float* b2 = (const float*)d_in[6];
  const float* W3 = (const float*)d_in[7];
  const float* b3 = (const float*)d_in[8];
  const float* Wr = (const float*)d_in[9];
  const float* br = (const float*)d_in[10];
  const float* Wo = (const float*)d_in[11];
  const float* bo = (const float*)d_in[12];
  float* out = (float*)d_out;

  const int N = in_sizes[0] / FD;
  const int E = in_sizes[1];

  char* ws = (char*)d_ws;
  size_t off = 0;
  auto alloc = [&](size_t bytes) -> void* {
    void* p = ws + off;
    off += (bytes + 255) & ~size_t(255);
    return p;
  };
  int* deg_out = (int*)alloc((size_t)N * 4);
  int* deg_in  = (int*)alloc((size_t)N * 4);
  int* cursor  = (int*)alloc((size_t)N * 4);
  int* row_ptr = (int*)alloc((size_t)(N + 1) * 4);
  float* d_src = (float*)alloc((size_t)N * 4);
  float* d_dst = (float*)alloc((size_t)N * 4);
  int* esrc    = (int*)alloc((size_t)E * 4);
  float* t0    = (float*)alloc((size_t)N * FD * 4);
  float* t1    = (float*)alloc((size_t)N * FD * 4);
  float* resb  = (float*)alloc((size_t)N * FD * 4);

  hipMemsetAsync(deg_out, 0, (size_t)N * 4, stream);
  hipMemsetAsync(deg_in, 0, (size_t)N * 4, stream);
  hipMemsetAsync(cursor, 0, (size_t)N * 4, stream);

  int gE = (E + 255) / 256;
  int gN = (N + 255) / 256;
  k_deg<<<gE, 256, 0, stream>>>(src, dst, deg_out, deg_in, E);
  k_norm<<<gN, 256, 0, stream>>>(deg_out, deg_in, d_src, d_dst, N);
  k_scan<<<1, 1024, 0, stream>>>(deg_in, row_ptr, N);
  k_fill<<<gE, 256, 0, stream>>>(src, dst, row_ptr, cursor, esrc, E);

  dim3 g128((N + 63) / 64, 2);
  dim3 g64((N + 63) / 64, 1);
  int gA = (N + 3) / 4;

  // res = x @ Wr + br
  k_gemm<FD, false, true><<<g128, 256, 0, stream>>>(x, Wr, br, nullptr, resb, N);
  // layer 1
  k_gemm<FD, true, false><<<g128, 256, 0, stream>>>(x, W1, nullptr, d_src, t0, N);
  k_agg<true, false><<<gA, 256, 0, stream>>>(t0, row_ptr, esrc, d_dst, b1, nullptr, t1, N);
  // layer 2
  k_gemm<FD, true, false><<<g128, 256, 0, stream>>>(t1, W2, nullptr, d_src, t0, N);
  k_agg<true, false><<<gA, 256, 0, stream>>>(t0, row_ptr, esrc, d_dst, b2, nullptr, t1, N);
  // layer 3 + residual + relu
  k_gemm<FD, true, false><<<g128, 256, 0, stream>>>(t1, W3, nullptr, d_src, t0, N);
  k_agg<true, true><<<gA, 256, 0, stream>>>(t0, row_ptr, esrc, d_dst, b3, resb, t1, N);
  // out = t1 @ Wo + bo
  k_gemm<CO, false, true><<<g64, 256, 0, stream>>>(t1, Wo, bo, nullptr, out, N);
}

// Round 2
// 467.575 us; speedup vs baseline: 1.3648x; 1.3648x over previous
//
#include <hip/hip_runtime.h>
#include <cstdint>
#include <cstddef>

#define FD 128
#define CO 64

// ---------------- CSR build ----------------

__global__ __launch_bounds__(256) void k_deg(const int* __restrict__ src,
                                             const int* __restrict__ dst,
                                             int* __restrict__ deg_out,
                                             int* __restrict__ deg_in, int E) {
  int e = blockIdx.x * 256 + threadIdx.x;
  if (e < E) {
    atomicAdd(&deg_out[src[e]], 1);
    atomicAdd(&deg_in[dst[e]], 1);
  }
}

__global__ __launch_bounds__(256) void k_norm(const int* __restrict__ deg_out,
                                              const int* __restrict__ deg_in,
                                              float* __restrict__ d_src,
                                              float* __restrict__ d_dst, int N) {
  int i = blockIdx.x * 256 + threadIdx.x;
  if (i < N) {
    int a = deg_out[i];
    int b = deg_in[i];
    d_src[i] = rsqrtf((float)(a > 0 ? a : 1));
    d_dst[i] = rsqrtf((float)(b > 0 ? b : 1));
  }
}

// ---- 3-phase multi-block exclusive scan of deg_in -> row_ptr ----

// phase 1: per-block (256-elem) sums
__global__ __launch_bounds__(256) void k_bsum(const int* __restrict__ deg,
                                              int* __restrict__ bsum, int N) {
  __shared__ int red[256];
  int tid = threadIdx.x;
  int i = blockIdx.x * 256 + tid;
  red[tid] = (i < N) ? deg[i] : 0;
  __syncthreads();
  for (int o = 128; o > 0; o >>= 1) {
    if (tid < o) red[tid] += red[tid + o];
    __syncthreads();
  }
  if (tid == 0) bsum[blockIdx.x] = red[0];
}

// phase 2: single-block exclusive scan of block sums (nb <= 1024)
__global__ __launch_bounds__(1024) void k_bscan(const int* __restrict__ bsum,
                                                int* __restrict__ boff, int nb) {
  __shared__ int s[1024];
  int tid = threadIdx.x;
  int v = (tid < nb) ? bsum[tid] : 0;
  s[tid] = v;
  __syncthreads();
  for (int o = 1; o < 1024; o <<= 1) {
    int t = (tid >= o) ? s[tid - o] : 0;
    __syncthreads();
    s[tid] += t;
    __syncthreads();
  }
  if (tid < nb) boff[tid] = s[tid] - v;  // exclusive
}

// phase 3: per-block exclusive scan + block offset -> row_ptr
__global__ __launch_bounds__(256) void k_rowptr(const int* __restrict__ deg,
                                                const int* __restrict__ boff,
                                                int* __restrict__ row_ptr,
                                                int N, int E) {
  __shared__ int s[256];
  int tid = threadIdx.x;
  int i = blockIdx.x * 256 + tid;
  int v = (i < N) ? deg[i] : 0;
  s[tid] = v;
  __syncthreads();
  for (int o = 1; o < 256; o <<= 1) {
    int t = (tid >= o) ? s[tid - o] : 0;
    __syncthreads();
    s[tid] += t;
    __syncthreads();
  }
  if (i < N) row_ptr[i] = boff[blockIdx.x] + s[tid] - v;
  if (i == 0) row_ptr[N] = E;
}

__global__ __launch_bounds__(256) void k_fill(const int* __restrict__ src,
                                              const int* __restrict__ dst,
                                              const int* __restrict__ row_ptr,
                                              int* __restrict__ cursor,
                                              int* __restrict__ esrc, int E) {
  int e = blockIdx.x * 256 + threadIdx.x;
  if (e < E) {
    int d = dst[e];
    int pos = row_ptr[d] + atomicAdd(&cursor[d], 1);
    esrc[pos] = src[e];
  }
}

// ---------------- GEMM: out[N][NCW] = (A (*dsc rows)) @ W (+ bias) ----------------
// tile: 64 rows x 64 cols per block; grid.y selects the 64-col slice.

template <int NCW, bool SCALE, bool BIAS>
__global__ __launch_bounds__(256) void k_gemm(const float* __restrict__ A,
                                              const float* __restrict__ W,
                                              const float* __restrict__ bias,
                                              const float* __restrict__ dsc,
                                              float* __restrict__ out, int N) {
  __shared__ float Alds[64][FD + 4];
  __shared__ float Wlds[FD][64];
  int tid = threadIdx.x;
  int rowBase = blockIdx.x * 64;
  int colBase = blockIdx.y * 64;

  for (int i = tid; i < FD * 16; i += 256) {
    int r = i >> 4, c4 = i & 15;
    float4 w = *(const float4*)(W + (size_t)r * NCW + colBase + c4 * 4);
    *(float4*)(&Wlds[r][c4 * 4]) = w;
  }
  for (int i = tid; i < 64 * 32; i += 256) {
    int r = i >> 5, c4 = i & 31;
    int gr = rowBase + r;
    float4 a = make_float4(0.f, 0.f, 0.f, 0.f);
    if (gr < N) {
      a = *(const float4*)(A + (size_t)gr * FD + c4 * 4);
      if (SCALE) {
        float s = dsc[gr];
        a.x *= s; a.y *= s; a.z *= s; a.w *= s;
      }
    }
    *(float4*)(&Alds[r][c4 * 4]) = a;
  }
  __syncthreads();

  int tx = tid & 15, ty = tid >> 4;
  int c0 = tx * 4, r0 = ty * 4;
  float acc[4][4] = {{0.f}};

#pragma unroll 8
  for (int k = 0; k < FD; k++) {
    float4 w = *(const float4*)(&Wlds[k][c0]);
    float a0 = Alds[r0 + 0][k];
    float a1 = Alds[r0 + 1][k];
    float a2 = Alds[r0 + 2][k];
    float a3 = Alds[r0 + 3][k];
    acc[0][0] += a0 * w.x; acc[0][1] += a0 * w.y; acc[0][2] += a0 * w.z; acc[0][3] += a0 * w.w;
    acc[1][0] += a1 * w.x; acc[1][1] += a1 * w.y; acc[1][2] += a1 * w.z; acc[1][3] += a1 * w.w;
    acc[2][0] += a2 * w.x; acc[2][1] += a2 * w.y; acc[2][2] += a2 * w.z; acc[2][3] += a2 * w.w;
    acc[3][0] += a3 * w.x; acc[3][1] += a3 * w.y; acc[3][2] += a3 * w.z; acc[3][3] += a3 * w.w;
  }

  float4 bv = make_float4(0.f, 0.f, 0.f, 0.f);
  if (BIAS) bv = *(const float4*)(bias + colBase + c0);
#pragma unroll
  for (int i = 0; i < 4; i++) {
    int gr = rowBase + r0 + i;
    if (gr < N) {
      float4 o;
      o.x = acc[i][0] + bv.x;
      o.y = acc[i][1] + bv.y;
      o.z = acc[i][2] + bv.z;
      o.w = acc[i][3] + bv.w;
      *(float4*)(out + (size_t)gr * NCW + colBase + c0) = o;
    }
  }
}

// ---------------- Aggregation ----------------
// one wave (64 lanes) per node, float2 per lane covers 128 features.
// 4-way edge unroll: independent row loads overlap (MLP), edge indices are
// wave-uniform -> scalar loads.

template <bool RELU, bool RES>
__global__ __launch_bounds__(256) void k_agg(const float* __restrict__ h,
                                             const int* __restrict__ row_ptr,
                                             const int* __restrict__ esrc,
                                             const float* __restrict__ d_dst,
                                             const float* __restrict__ bias,
                                             const float* __restrict__ res,
                                             float* __restrict__ out, int N) {
  int node = blockIdx.x * 4 + (threadIdx.x >> 6);
  int lane = threadIdx.x & 63;
  if (node >= N) return;
  int beg = row_ptr[node], end = row_ptr[node + 1];
  const float2* h2 = (const float2*)h;
  float ax = 0.f, ay = 0.f;
  int e = beg;
  for (; e + 4 <= end; e += 4) {
    int s0 = esrc[e + 0];
    int s1 = esrc[e + 1];
    int s2 = esrc[e + 2];
    int s3 = esrc[e + 3];
    float2 v0 = h2[(size_t)s0 * 64 + lane];
    float2 v1 = h2[(size_t)s1 * 64 + lane];
    float2 v2 = h2[(size_t)s2 * 64 + lane];
    float2 v3 = h2[(size_t)s3 * 64 + lane];
    ax += v0.x + v1.x + v2.x + v3.x;
    ay += v0.y + v1.y + v2.y + v3.y;
  }
  for (; e < end; e++) {
    int s = esrc[e];
    float2 v = h2[(size_t)s * 64 + lane];
    ax += v.x;
    ay += v.y;
  }
  float d = d_dst[node];
  float2 b = ((const float2*)bias)[lane];
  float vx = ax * d + b.x;
  float vy = ay * d + b.y;
  if (RES) {
    float2 r = ((const float2*)res)[(size_t)node * 64 + lane];
    vx += r.x;
    vy += r.y;
  }
  if (RELU) {
    vx = fmaxf(vx, 0.f);
    vy = fmaxf(vy, 0.f);
  }
  float2 o;
  o.x = vx;
  o.y = vy;
  ((float2*)out)[(size_t)node * 64 + lane] = o;
}

// ---------------- launch ----------------

extern "C" void kernel_launch(void* const* d_in, const int* in_sizes, int n_in,
                              void* d_out, int out_size, void* d_ws, size_t ws_size,
                              hipStream_t stream) {
  (void)n_in; (void)out_size; (void)ws_size;
  const float* x  = (const float*)d_in[0];
  const int*   src = (const int*)d_in[1];
  const int*   dst = (const int*)d_in[2];
  const float* W1 = (const float*)d_in[3];
  const float* b1 = (const float*)d_in[4];
  const float* W2 = (const float*)d_in[5];
  const float* b2 = (const float*)d_in[6];
  const float* W3 = (const float*)d_in[7];
  const float* b3 = (const float*)d_in[8];
  const float* Wr = (const float*)d_in[9];
  const float* br = (const float*)d_in[10];
  const float* Wo = (const float*)d_in[11];
  const float* bo = (const float*)d_in[12];
  float* out = (float*)d_out;

  const int N = in_sizes[0] / FD;
  const int E = in_sizes[1];

  char* ws = (char*)d_ws;
  size_t off = 0;
  auto alloc = [&](size_t bytes) -> void* {
    void* p = ws + off;
    off += (bytes + 255) & ~size_t(255);
    return p;
  };
  int* deg_out = (int*)alloc((size_t)N * 4);
  int* deg_in  = (int*)alloc((size_t)N * 4);
  int* cursor  = (int*)alloc((size_t)N * 4);
  int* row_ptr = (int*)alloc((size_t)(N + 1) * 4);
  int* bsum    = (int*)alloc(1024 * 4);
  int* boff    = (int*)alloc(1024 * 4);
  float* d_src = (float*)alloc((size_t)N * 4);
  float* d_dst = (float*)alloc((size_t)N * 4);
  int* esrc    = (int*)alloc((size_t)E * 4);
  float* t0    = (float*)alloc((size_t)N * FD * 4);
  float* t1    = (float*)alloc((size_t)N * FD * 4);
  float* resb  = (float*)alloc((size_t)N * FD * 4);

  hipMemsetAsync(deg_out, 0, (size_t)N * 4, stream);
  hipMemsetAsync(deg_in, 0, (size_t)N * 4, stream);
  hipMemsetAsync(cursor, 0, (size_t)N * 4, stream);

  int gE = (E + 255) / 256;
  int gN = (N + 255) / 256;
  int nb = gN;  // blocks in scan phase (196 for N=50000, <=1024)

  k_deg<<<gE, 256, 0, stream>>>(src, dst, deg_out, deg_in, E);
  k_norm<<<gN, 256, 0, stream>>>(deg_out, deg_in, d_src, d_dst, N);
  k_bsum<<<nb, 256, 0, stream>>>(deg_in, bsum, N);
  k_bscan<<<1, 1024, 0, stream>>>(bsum, boff, nb);
  k_rowptr<<<nb, 256, 0, stream>>>(deg_in, boff, row_ptr, N, E);
  k_fill<<<gE, 256, 0, stream>>>(src, dst, row_ptr, cursor, esrc, E);

  dim3 g128((N + 63) / 64, 2);
  dim3 g64((N + 63) / 64, 1);
  int gA = (N + 3) / 4;

  // res = x @ Wr + br
  k_gemm<FD, false, true><<<g128, 256, 0, stream>>>(x, Wr, br, nullptr, resb, N);
  // layer 1
  k_gemm<FD, true, false><<<g128, 256, 0, stream>>>(x, W1, nullptr, d_src, t0, N);
  k_agg<true, false><<<gA, 256, 0, stream>>>(t0, row_ptr, esrc, d_dst, b1, nullptr, t1, N);
  // layer 2
  k_gemm<FD, true, false><<<g128, 256, 0, stream>>>(t1, W2, nullptr, d_src, t0, N);
  k_agg<true, false><<<gA, 256, 0, stream>>>(t0, row_ptr, esrc, d_dst, b2, nullptr, t1, N);
  // layer 3 + residual + relu
  k_gemm<FD, true, false><<<g128, 256, 0, stream>>>(t1, W3, nullptr, d_src, t0, N);
  k_agg<true, true><<<gA, 256, 0, stream>>>(t0, row_ptr, esrc, d_dst, b3, resb, t1, N);
  // out = t1 @ Wo + bo
  k_gemm<CO, false, true><<<g64, 256, 0, stream>>>(t1, Wo, bo, nullptr, out, N);
}

// Round 3
// 417.974 us; speedup vs baseline: 1.5268x; 1.1187x over previous
//
#include <hip/hip_runtime.h>
#include <cstdint>
#include <cstddef>

#define FD 128
#define CO 64

typedef short bf16x8 __attribute__((ext_vector_type(8)));
typedef float f32x4 __attribute__((ext_vector_type(4)));

__device__ __forceinline__ unsigned short f2bf(float f) {
  unsigned u = __float_as_uint(f);
  unsigned r = u + 0x7fffu + ((u >> 16) & 1u);
  return (unsigned short)(r >> 16);
}
__device__ __forceinline__ float bf2f(unsigned short b) {
  return __uint_as_float((unsigned)b << 16);
}

// ---------------- CSR build ----------------

__global__ __launch_bounds__(256) void k_deg(const int* __restrict__ src,
                                             const int* __restrict__ dst,
                                             int* __restrict__ deg_out,
                                             int* __restrict__ deg_in, int E) {
  int e = blockIdx.x * 256 + threadIdx.x;
  if (e < E) {
    atomicAdd(&deg_out[src[e]], 1);
    atomicAdd(&deg_in[dst[e]], 1);
  }
}

__global__ __launch_bounds__(256) void k_norm(const int* __restrict__ deg_out,
                                              const int* __restrict__ deg_in,
                                              float* __restrict__ d_src,
                                              float* __restrict__ d_dst, int N) {
  int i = blockIdx.x * 256 + threadIdx.x;
  if (i < N) {
    int a = deg_out[i];
    int b = deg_in[i];
    d_src[i] = rsqrtf((float)(a > 0 ? a : 1));
    d_dst[i] = rsqrtf((float)(b > 0 ? b : 1));
  }
}

// phase 1: per-block (256-elem) sums
__global__ __launch_bounds__(256) void k_bsum(const int* __restrict__ deg,
                                              int* __restrict__ bsum, int N) {
  __shared__ int red[256];
  int tid = threadIdx.x;
  int i = blockIdx.x * 256 + tid;
  red[tid] = (i < N) ? deg[i] : 0;
  __syncthreads();
  for (int o = 128; o > 0; o >>= 1) {
    if (tid < o) red[tid] += red[tid + o];
    __syncthreads();
  }
  if (tid == 0) bsum[blockIdx.x] = red[0];
}

// phase 2: single-block exclusive scan of block sums (nb <= 1024)
__global__ __launch_bounds__(1024) void k_bscan(const int* __restrict__ bsum,
                                                int* __restrict__ boff, int nb) {
  __shared__ int s[1024];
  int tid = threadIdx.x;
  int v = (tid < nb) ? bsum[tid] : 0;
  s[tid] = v;
  __syncthreads();
  for (int o = 1; o < 1024; o <<= 1) {
    int t = (tid >= o) ? s[tid - o] : 0;
    __syncthreads();
    s[tid] += t;
    __syncthreads();
  }
  if (tid < nb) boff[tid] = s[tid] - v;  // exclusive
}

// phase 3: per-block exclusive scan + block offset -> row_ptr AND cursor
__global__ __launch_bounds__(256) void k_rowptr(const int* __restrict__ deg,
                                                const int* __restrict__ boff,
                                                int* __restrict__ row_ptr,
                                                int* __restrict__ cursor,
                                                int N, int E) {
  __shared__ int s[256];
  int tid = threadIdx.x;
  int i = blockIdx.x * 256 + tid;
  int v = (i < N) ? deg[i] : 0;
  s[tid] = v;
  __syncthreads();
  for (int o = 1; o < 256; o <<= 1) {
    int t = (tid >= o) ? s[tid - o] : 0;
    __syncthreads();
    s[tid] += t;
    __syncthreads();
  }
  if (i < N) {
    int rp = boff[blockIdx.x] + s[tid] - v;
    row_ptr[i] = rp;
    cursor[i] = rp;
  }
  if (i == 0) row_ptr[N] = E;
}

__global__ __launch_bounds__(256) void k_fill(const int* __restrict__ src,
                                              const int* __restrict__ dst,
                                              int* __restrict__ cursor,
                                              int* __restrict__ esrc, int E) {
  int e = blockIdx.x * 256 + threadIdx.x;
  if (e < E) {
    int pos = atomicAdd(&cursor[dst[e]], 1);
    esrc[pos] = src[e];
  }
}

// ---------------- MFMA GEMM: out[N][NCW] = (A (*dsc rows)) @ W (+ bias) ----------------
// split-bf16: a = hi + lo; a*b = hi*hi + hi*lo + lo*hi (error ~2^-18 rel).
// LDS layout frag-packed: [kc][row][8] bf16 so a/b-frag reads are consecutive
// 16B per lane (conflict-free ds_read_b128).
// Block: 256 thr = 4 waves, tile 64x64, wave tile 32x32 (2x2 frags 16x16x32).

template <int NCW, bool SCALE, bool BIAS>
__global__ __launch_bounds__(256) void k_gemm(const float* __restrict__ A,
                                              const float* __restrict__ W,
                                              const float* __restrict__ bias,
                                              const float* __restrict__ dsc,
                                              float* __restrict__ out, int N) {
  extern __shared__ char smem[];
  bf16x8* Ah = (bf16x8*)smem;   // [16 kc][64 row] 16B slots
  bf16x8* Al = Ah + 1024;
  bf16x8* Wh = Al + 1024;       // [16 kc][64 col]
  bf16x8* Wl = Wh + 1024;
  int tid = threadIdx.x;
  int rowBase = blockIdx.x * 64;
  int colBase = blockIdx.y * 64;

  // stage W tile (strided per-j reads are coalesced across lanes; W is L2-hot)
#pragma unroll
  for (int t = 0; t < 4; t++) {
    int p = t * 256 + tid;
    int kc = p >> 6, col = p & 63;
    bf16x8 h, l;
#pragma unroll
    for (int j = 0; j < 8; j++) {
      float v = W[(size_t)(kc * 8 + j) * NCW + colBase + col];
      unsigned short hb = f2bf(v);
      h[j] = (short)hb;
      l[j] = (short)f2bf(v - bf2f(hb));
    }
    Wh[kc * 64 + col] = h;
    Wl[kc * 64 + col] = l;
  }
  // stage A tile
#pragma unroll
  for (int t = 0; t < 4; t++) {
    int p = t * 256 + tid;
    int kc = p >> 6, row = p & 63;
    int gr = rowBase + row;
    float4 u = make_float4(0.f, 0.f, 0.f, 0.f);
    float4 v = make_float4(0.f, 0.f, 0.f, 0.f);
    float s = 1.f;
    if (gr < N) {
      const float4* A4 = (const float4*)(A + (size_t)gr * FD + kc * 8);
      u = A4[0];
      v = A4[1];
      if (SCALE) s = dsc[gr];
    }
    float vals[8] = {u.x, u.y, u.z, u.w, v.x, v.y, v.z, v.w};
    bf16x8 h, l;
#pragma unroll
    for (int j = 0; j < 8; j++) {
      float f = SCALE ? vals[j] * s : vals[j];
      unsigned short hb = f2bf(f);
      h[j] = (short)hb;
      l[j] = (short)f2bf(f - bf2f(hb));
    }
    Ah[kc * 64 + row] = h;
    Al[kc * 64 + row] = l;
  }
  __syncthreads();

  int wv = tid >> 6, lane = tid & 63;
  int wr = (wv >> 1) * 32, wc = (wv & 1) * 32;
  int lhi = lane >> 4, llo = lane & 15;
  f32x4 acc[2][2] = {};

#pragma unroll
  for (int ks = 0; ks < 4; ks++) {
    int kcg = ks * 4 + lhi;
    int abase = kcg * 64 + wr + llo;
    int bbase = kcg * 64 + wc + llo;
    bf16x8 ah0 = Ah[abase];
    bf16x8 ah1 = Ah[abase + 16];
    bf16x8 al0 = Al[abase];
    bf16x8 al1 = Al[abase + 16];
    bf16x8 bh0 = Wh[bbase];
    bf16x8 bh1 = Wh[bbase + 16];
    bf16x8 bl0 = Wl[bbase];
    bf16x8 bl1 = Wl[bbase + 16];
    acc[0][0] = __builtin_amdgcn_mfma_f32_16x16x32_bf16(ah0, bh0, acc[0][0], 0, 0, 0);
    acc[0][1] = __builtin_amdgcn_mfma_f32_16x16x32_bf16(ah0, bh1, acc[0][1], 0, 0, 0);
    acc[1][0] = __builtin_amdgcn_mfma_f32_16x16x32_bf16(ah1, bh0, acc[1][0], 0, 0, 0);
    acc[1][1] = __builtin_amdgcn_mfma_f32_16x16x32_bf16(ah1, bh1, acc[1][1], 0, 0, 0);
    acc[0][0] = __builtin_amdgcn_mfma_f32_16x16x32_bf16(ah0, bl0, acc[0][0], 0, 0, 0);
    acc[0][1] = __builtin_amdgcn_mfma_f32_16x16x32_bf16(ah0, bl1, acc[0][1], 0, 0, 0);
    acc[1][0] = __builtin_amdgcn_mfma_f32_16x16x32_bf16(ah1, bl0, acc[1][0], 0, 0, 0);
    acc[1][1] = __builtin_amdgcn_mfma_f32_16x16x32_bf16(ah1, bl1, acc[1][1], 0, 0, 0);
    acc[0][0] = __builtin_amdgcn_mfma_f32_16x16x32_bf16(al0, bh0, acc[0][0], 0, 0, 0);
    acc[0][1] = __builtin_amdgcn_mfma_f32_16x16x32_bf16(al0, bh1, acc[0][1], 0, 0, 0);
    acc[1][0] = __builtin_amdgcn_mfma_f32_16x16x32_bf16(al1, bh0, acc[1][0], 0, 0, 0);
    acc[1][1] = __builtin_amdgcn_mfma_f32_16x16x32_bf16(al1, bh1, acc[1][1], 0, 0, 0);
  }

  // epilogue: C/D layout col=lane&15, row=(lane>>4)*4+reg
  float bv0 = 0.f, bv1 = 0.f;
  if (BIAS) {
    bv0 = bias[colBase + wc + llo];
    bv1 = bias[colBase + wc + 16 + llo];
  }
#pragma unroll
  for (int mf = 0; mf < 2; mf++) {
#pragma unroll
    for (int nf = 0; nf < 2; nf++) {
      float bv = nf ? bv1 : bv0;
      int col = colBase + wc + nf * 16 + llo;
#pragma unroll
      for (int r = 0; r < 4; r++) {
        int row = rowBase + wr + mf * 16 + lhi * 4 + r;
        if (row < N) out[(size_t)row * NCW + col] = acc[mf][nf][r] + bv;
      }
    }
  }
}

// ---------------- Aggregation ----------------

template <bool RELU, bool RES>
__global__ __launch_bounds__(256) void k_agg(const float* __restrict__ h,
                                             const int* __restrict__ row_ptr,
                                             const int* __restrict__ esrc,
                                             const float* __restrict__ d_dst,
                                             const float* __restrict__ bias,
                                             const float* __restrict__ res,
                                             float* __restrict__ out, int N) {
  int node = blockIdx.x * 4 + (threadIdx.x >> 6);
  int lane = threadIdx.x & 63;
  if (node >= N) return;
  int beg = row_ptr[node], end = row_ptr[node + 1];
  const float2* h2 = (const float2*)h;
  float ax = 0.f, ay = 0.f;
  int e = beg;
  for (; e + 4 <= end; e += 4) {
    int s0 = esrc[e + 0];
    int s1 = esrc[e + 1];
    int s2 = esrc[e + 2];
    int s3 = esrc[e + 3];
    float2 v0 = h2[(size_t)s0 * 64 + lane];
    float2 v1 = h2[(size_t)s1 * 64 + lane];
    float2 v2 = h2[(size_t)s2 * 64 + lane];
    float2 v3 = h2[(size_t)s3 * 64 + lane];
    ax += v0.x + v1.x + v2.x + v3.x;
    ay += v0.y + v1.y + v2.y + v3.y;
  }
  for (; e < end; e++) {
    int s = esrc[e];
    float2 v = h2[(size_t)s * 64 + lane];
    ax += v.x;
    ay += v.y;
  }
  float d = d_dst[node];
  float2 b = ((const float2*)bias)[lane];
  float vx = ax * d + b.x;
  float vy = ay * d + b.y;
  if (RES) {
    float2 r = ((const float2*)res)[(size_t)node * 64 + lane];
    vx += r.x;
    vy += r.y;
  }
  if (RELU) {
    vx = fmaxf(vx, 0.f);
    vy = fmaxf(vy, 0.f);
  }
  float2 o;
  o.x = vx;
  o.y = vy;
  ((float2*)out)[(size_t)node * 64 + lane] = o;
}

// ---------------- launch ----------------

extern "C" void kernel_launch(void* const* d_in, const int* in_sizes, int n_in,
                              void* d_out, int out_size, void* d_ws, size_t ws_size,
                              hipStream_t stream) {
  (void)n_in; (void)out_size; (void)ws_size;
  const float* x  = (const float*)d_in[0];
  const int*   src = (const int*)d_in[1];
  const int*   dst = (const int*)d_in[2];
  const float* W1 = (const float*)d_in[3];
  const float* b1 = (const float*)d_in[4];
  const float* W2 = (const float*)d_in[5];
  const float* b2 = (const float*)d_in[6];
  const float* W3 = (const float*)d_in[7];
  const float* b3 = (const float*)d_in[8];
  const float* Wr = (const float*)d_in[9];
  const float* br = (const float*)d_in[10];
  const float* Wo = (const float*)d_in[11];
  const float* bo = (const float*)d_in[12];
  float* out = (float*)d_out;

  const int N = in_sizes[0] / FD;
  const int E = in_sizes[1];

  char* ws = (char*)d_ws;
  size_t off = 0;
  auto alloc = [&](size_t bytes) -> void* {
    void* p = ws + off;
    off += (bytes + 255) & ~size_t(255);
    return p;
  };
  int* deg_out = (int*)alloc((size_t)N * 4);
  int* deg_in  = (int*)alloc((size_t)N * 4);
  int* cursor  = (int*)alloc((size_t)N * 4);
  int* row_ptr = (int*)alloc((size_t)(N + 1) * 4);
  int* bsum    = (int*)alloc(1024 * 4);
  int* boff    = (int*)alloc(1024 * 4);
  float* d_src = (float*)alloc((size_t)N * 4);
  float* d_dst = (float*)alloc((size_t)N * 4);
  int* esrc    = (int*)alloc((size_t)E * 4);
  float* t0    = (float*)alloc((size_t)N * FD * 4);
  float* t1    = (float*)alloc((size_t)N * FD * 4);
  float* resb  = (float*)alloc((size_t)N * FD * 4);

  hipMemsetAsync(deg_out, 0, (size_t)N * 4, stream);
  hipMemsetAsync(deg_in, 0, (size_t)N * 4, stream);

  int gE = (E + 255) / 256;
  int gN = (N + 255) / 256;
  int nb = gN;  // <= 1024

  k_deg<<<gE, 256, 0, stream>>>(src, dst, deg_out, deg_in, E);
  k_norm<<<gN, 256, 0, stream>>>(deg_out, deg_in, d_src, d_dst, N);
  k_bsum<<<nb, 256, 0, stream>>>(deg_in, bsum, N);
  k_bscan<<<1, 1024, 0, stream>>>(bsum, boff, nb);
  k_rowptr<<<nb, 256, 0, stream>>>(deg_in, boff, row_ptr, cursor, N, E);
  k_fill<<<gE, 256, 0, stream>>>(src, dst, cursor, esrc, E);

  dim3 g128((N + 63) / 64, 2);
  dim3 g64((N + 63) / 64, 1);
  int gA = (N + 3) / 4;
  const size_t LDS = 65536;

  // res = x @ Wr + br
  k_gemm<FD, false, true><<<g128, 256, LDS, stream>>>(x, Wr, br, nullptr, resb, N);
  // layer 1
  k_gemm<FD, true, false><<<g128, 256, LDS, stream>>>(x, W1, nullptr, d_src, t0, N);
  k_agg<true, false><<<gA, 256, 0, stream>>>(t0, row_ptr, esrc, d_dst, b1, nullptr, t1, N);
  // layer 2
  k_gemm<FD, true, false><<<g128, 256, LDS, stream>>>(t1, W2, nullptr, d_src, t0, N);
  k_agg<true, false><<<gA, 256, 0, stream>>>(t0, row_ptr, esrc, d_dst, b2, nullptr, t1, N);
  // layer 3 + residual + relu
  k_gemm<FD, true, false><<<g128, 256, LDS, stream>>>(t1, W3, nullptr, d_src, t0, N);
  k_agg<true, true><<<gA, 256, 0, stream>>>(t0, row_ptr, esrc, d_dst, b3, resb, t1, N);
  // out = t1 @ Wo + bo
  k_gemm<CO, false, true><<<g64, 256, LDS, stream>>>(t1, Wo, bo, nullptr, out, N);
}

// Round 4
// 302.020 us; speedup vs baseline: 2.1129x; 1.3839x over previous
//
#include <hip/hip_runtime.h>
#include <cstdint>
#include <cstddef>

#define FD 128
#define CO 64

typedef short bf16x8 __attribute__((ext_vector_type(8)));
typedef float f32x4 __attribute__((ext_vector_type(4)));
typedef unsigned int uint32;

__device__ __forceinline__ unsigned short f2bf(float f) {
  unsigned u = __float_as_uint(f);
  unsigned r = u + 0x7fffu + ((u >> 16) & 1u);
  return (unsigned short)(r >> 16);
}
__device__ __forceinline__ float bf2f(unsigned short b) {
  return __uint_as_float((unsigned)b << 16);
}

// ---------------- CSR build ----------------

// degrees + per-edge rank within its dst bucket (atomic return value)
__global__ __launch_bounds__(256) void k_degrank(const int* __restrict__ src,
                                                 const int* __restrict__ dst,
                                                 int* __restrict__ deg_out,
                                                 int* __restrict__ deg_in,
                                                 int* __restrict__ erank, int E) {
  int e = blockIdx.x * 256 + threadIdx.x;
  if (e < E) {
    atomicAdd(&deg_out[src[e]], 1);
    erank[e] = atomicAdd(&deg_in[dst[e]], 1);
  }
}

__global__ __launch_bounds__(256) void k_norm(const int* __restrict__ deg_out,
                                              const int* __restrict__ deg_in,
                                              float* __restrict__ d_src,
                                              float* __restrict__ d_dst, int N) {
  int i = blockIdx.x * 256 + threadIdx.x;
  if (i < N) {
    int a = deg_out[i];
    int b = deg_in[i];
    d_src[i] = rsqrtf((float)(a > 0 ? a : 1));
    d_dst[i] = rsqrtf((float)(b > 0 ? b : 1));
  }
}

// phase 1: per-block (256-elem) sums
__global__ __launch_bounds__(256) void k_bsum(const int* __restrict__ deg,
                                              int* __restrict__ bsum, int N) {
  __shared__ int red[256];
  int tid = threadIdx.x;
  int i = blockIdx.x * 256 + tid;
  red[tid] = (i < N) ? deg[i] : 0;
  __syncthreads();
  for (int o = 128; o > 0; o >>= 1) {
    if (tid < o) red[tid] += red[tid + o];
    __syncthreads();
  }
  if (tid == 0) bsum[blockIdx.x] = red[0];
}

// phase 2: single-block exclusive scan of block sums (nb <= 1024)
__global__ __launch_bounds__(1024) void k_bscan(const int* __restrict__ bsum,
                                                int* __restrict__ boff, int nb) {
  __shared__ int s[1024];
  int tid = threadIdx.x;
  int v = (tid < nb) ? bsum[tid] : 0;
  s[tid] = v;
  __syncthreads();
  for (int o = 1; o < 1024; o <<= 1) {
    int t = (tid >= o) ? s[tid - o] : 0;
    __syncthreads();
    s[tid] += t;
    __syncthreads();
  }
  if (tid < nb) boff[tid] = s[tid] - v;  // exclusive
}

// phase 3: per-block exclusive scan + block offset -> row_ptr
__global__ __launch_bounds__(256) void k_rowptr(const int* __restrict__ deg,
                                                const int* __restrict__ boff,
                                                int* __restrict__ row_ptr,
                                                int N, int E) {
  __shared__ int s[256];
  int tid = threadIdx.x;
  int i = blockIdx.x * 256 + tid;
  int v = (i < N) ? deg[i] : 0;
  s[tid] = v;
  __syncthreads();
  for (int o = 1; o < 256; o <<= 1) {
    int t = (tid >= o) ? s[tid - o] : 0;
    __syncthreads();
    s[tid] += t;
    __syncthreads();
  }
  if (i < N) row_ptr[i] = boff[blockIdx.x] + s[tid] - v;
  if (i == 0) row_ptr[N] = E;
}

// scatter edges into CSR slots — no atomics (rank precomputed)
__global__ __launch_bounds__(256) void k_place(const int* __restrict__ src,
                                               const int* __restrict__ dst,
                                               const int* __restrict__ erank,
                                               const int* __restrict__ row_ptr,
                                               int* __restrict__ esrc, int E) {
  int e = blockIdx.x * 256 + threadIdx.x;
  if (e < E) esrc[row_ptr[dst[e]] + erank[e]] = src[e];
}

// ---------------- MFMA GEMM ----------------
// A: bf16 [N][128] (ABF16) or fp32 [N][128] (rounded to bf16 at staging).
// W: fp32, split hi/lo bf16 (weight error ~2^-18).
// epilogue: v = acc * (SCALE ? rscale[row] : 1) + (BIAS ? bias[col] : 0)
//           stored bf16 (OUTBF16) or fp32.
// Block: 4 waves, tile 64x64; wave tile 32x32 (2x2 frags of 16x16x32).

template <int NCW, bool ABF16, bool SCALE, bool BIAS, bool OUTBF16>
__global__ __launch_bounds__(256) void k_gemm(const void* __restrict__ Av,
                                              const float* __restrict__ W,
                                              const float* __restrict__ bias,
                                              const float* __restrict__ rscale,
                                              void* __restrict__ outv, int N) {
  extern __shared__ char smem[];
  bf16x8* Ah = (bf16x8*)smem;   // [16 kc][64 row] 16B slots = 16KB
  bf16x8* Wh = Ah + 1024;       // [16 kc][64 col] 16KB
  bf16x8* Wl = Wh + 1024;       // 16KB
  int tid = threadIdx.x;
  int rowBase = blockIdx.x * 64;
  int colBase = blockIdx.y * 64;

  // stage W tile hi/lo
#pragma unroll
  for (int t = 0; t < 4; t++) {
    int p = t * 256 + tid;
    int kc = p >> 6, col = p & 63;
    bf16x8 h, l;
#pragma unroll
    for (int j = 0; j < 8; j++) {
      float v = W[(size_t)(kc * 8 + j) * NCW + colBase + col];
      unsigned short hb = f2bf(v);
      h[j] = (short)hb;
      l[j] = (short)f2bf(v - bf2f(hb));
    }
    Wh[kc * 64 + col] = h;
    Wl[kc * 64 + col] = l;
  }
  // stage A tile (single bf16)
#pragma unroll
  for (int t = 0; t < 4; t++) {
    int p = t * 256 + tid;
    int kc = p >> 6, row = p & 63;
    int gr = rowBase + row;
    bf16x8 h = {0, 0, 0, 0, 0, 0, 0, 0};
    if (gr < N) {
      if (ABF16) {
        h = *(const bf16x8*)((const unsigned short*)Av + (size_t)gr * FD + kc * 8);
      } else {
        const float4* A4 = (const float4*)((const float*)Av + (size_t)gr * FD + kc * 8);
        float4 u = A4[0];
        float4 v = A4[1];
        float vals[8] = {u.x, u.y, u.z, u.w, v.x, v.y, v.z, v.w};
#pragma unroll
        for (int j = 0; j < 8; j++) h[j] = (short)f2bf(vals[j]);
      }
    }
    Ah[kc * 64 + row] = h;
  }
  __syncthreads();

  int wv = tid >> 6, lane = tid & 63;
  int wr = (wv >> 1) * 32, wc = (wv & 1) * 32;
  int lhi = lane >> 4, llo = lane & 15;
  f32x4 acc[2][2] = {};

#pragma unroll
  for (int ks = 0; ks < 4; ks++) {
    int kcg = ks * 4 + lhi;
    int abase = kcg * 64 + wr + llo;
    int bbase = kcg * 64 + wc + llo;
    bf16x8 a0 = Ah[abase];
    bf16x8 a1 = Ah[abase + 16];
    bf16x8 bh0 = Wh[bbase];
    bf16x8 bh1 = Wh[bbase + 16];
    bf16x8 bl0 = Wl[bbase];
    bf16x8 bl1 = Wl[bbase + 16];
    acc[0][0] = __builtin_amdgcn_mfma_f32_16x16x32_bf16(a0, bh0, acc[0][0], 0, 0, 0);
    acc[0][1] = __builtin_amdgcn_mfma_f32_16x16x32_bf16(a0, bh1, acc[0][1], 0, 0, 0);
    acc[1][0] = __builtin_amdgcn_mfma_f32_16x16x32_bf16(a1, bh0, acc[1][0], 0, 0, 0);
    acc[1][1] = __builtin_amdgcn_mfma_f32_16x16x32_bf16(a1, bh1, acc[1][1], 0, 0, 0);
    acc[0][0] = __builtin_amdgcn_mfma_f32_16x16x32_bf16(a0, bl0, acc[0][0], 0, 0, 0);
    acc[0][1] = __builtin_amdgcn_mfma_f32_16x16x32_bf16(a0, bl1, acc[0][1], 0, 0, 0);
    acc[1][0] = __builtin_amdgcn_mfma_f32_16x16x32_bf16(a1, bl0, acc[1][0], 0, 0, 0);
    acc[1][1] = __builtin_amdgcn_mfma_f32_16x16x32_bf16(a1, bl1, acc[1][1], 0, 0, 0);
  }

  // epilogue: C/D layout col=lane&15, row=(lane>>4)*4+reg
  float bv0 = 0.f, bv1 = 0.f;
  if (BIAS) {
    bv0 = bias[colBase + wc + llo];
    bv1 = bias[colBase + wc + 16 + llo];
  }
  float rs[2][4];
  if (SCALE) {
#pragma unroll
    for (int mf = 0; mf < 2; mf++)
#pragma unroll
      for (int r = 0; r < 4; r++) {
        int row = rowBase + wr + mf * 16 + lhi * 4 + r;
        rs[mf][r] = (row < N) ? rscale[row] : 0.f;
      }
  }
#pragma unroll
  for (int mf = 0; mf < 2; mf++) {
#pragma unroll
    for (int nf = 0; nf < 2; nf++) {
      float bv = nf ? bv1 : bv0;
      int col = colBase + wc + nf * 16 + llo;
#pragma unroll
      for (int r = 0; r < 4; r++) {
        int row = rowBase + wr + mf * 16 + lhi * 4 + r;
        if (row < N) {
          float v = acc[mf][nf][r];
          if (SCALE) v *= rs[mf][r];
          v += bv;
          if (OUTBF16)
            ((unsigned short*)outv)[(size_t)row * NCW + col] = f2bf(v);
          else
            ((float*)outv)[(size_t)row * NCW + col] = v;
        }
      }
    }
  }
}

// ---------------- Aggregation (bf16 rows) ----------------
// one wave per node; lane covers features (2*lane, 2*lane+1) as one uint.

template <bool RELU, bool RES>
__global__ __launch_bounds__(256) void k_agg(const unsigned short* __restrict__ h,
                                             const int* __restrict__ row_ptr,
                                             const int* __restrict__ esrc,
                                             const float* __restrict__ d_dst,
                                             const float* __restrict__ bias,
                                             const unsigned short* __restrict__ res,
                                             unsigned short* __restrict__ out, int N) {
  int node = blockIdx.x * 4 + (threadIdx.x >> 6);
  int lane = threadIdx.x & 63;
  if (node >= N) return;
  int beg = row_ptr[node], end = row_ptr[node + 1];
  const uint32* h4 = (const uint32*)h;
  float ax = 0.f, ay = 0.f;
  int e = beg;
  for (; e + 4 <= end; e += 4) {
    int s0 = esrc[e + 0];
    int s1 = esrc[e + 1];
    int s2 = esrc[e + 2];
    int s3 = esrc[e + 3];
    uint32 v0 = h4[(size_t)s0 * 64 + lane];
    uint32 v1 = h4[(size_t)s1 * 64 + lane];
    uint32 v2 = h4[(size_t)s2 * 64 + lane];
    uint32 v3 = h4[(size_t)s3 * 64 + lane];
    ax += bf2f((unsigned short)(v0 & 0xffff)) + bf2f((unsigned short)(v1 & 0xffff)) +
          bf2f((unsigned short)(v2 & 0xffff)) + bf2f((unsigned short)(v3 & 0xffff));
    ay += bf2f((unsigned short)(v0 >> 16)) + bf2f((unsigned short)(v1 >> 16)) +
          bf2f((unsigned short)(v2 >> 16)) + bf2f((unsigned short)(v3 >> 16));
  }
  for (; e < end; e++) {
    int s = esrc[e];
    uint32 v = h4[(size_t)s * 64 + lane];
    ax += bf2f((unsigned short)(v & 0xffff));
    ay += bf2f((unsigned short)(v >> 16));
  }
  float d = d_dst[node];
  float2 b = ((const float2*)bias)[lane];
  float vx = ax * d + b.x;
  float vy = ay * d + b.y;
  if (RES) {
    uint32 r = ((const uint32*)res)[(size_t)node * 64 + lane];
    vx += bf2f((unsigned short)(r & 0xffff));
    vy += bf2f((unsigned short)(r >> 16));
  }
  if (RELU) {
    vx = fmaxf(vx, 0.f);
    vy = fmaxf(vy, 0.f);
  }
  uint32 o = (uint32)f2bf(vx) | ((uint32)f2bf(vy) << 16);
  ((uint32*)out)[(size_t)node * 64 + lane] = o;
}

// ---------------- launch ----------------

extern "C" void kernel_launch(void* const* d_in, const int* in_sizes, int n_in,
                              void* d_out, int out_size, void* d_ws, size_t ws_size,
                              hipStream_t stream) {
  (void)n_in; (void)out_size; (void)ws_size;
  const float* x  = (const float*)d_in[0];
  const int*   src = (const int*)d_in[1];
  const int*   dst = (const int*)d_in[2];
  const float* W1 = (const float*)d_in[3];
  const float* b1 = (const float*)d_in[4];
  const float* W2 = (const float*)d_in[5];
  const float* b2 = (const float*)d_in[6];
  const float* W3 = (const float*)d_in[7];
  const float* b3 = (const float*)d_in[8];
  const float* Wr = (const float*)d_in[9];
  const float* br = (const float*)d_in[10];
  const float* Wo = (const float*)d_in[11];
  const float* bo = (const float*)d_in[12];
  float* out = (float*)d_out;

  const int N = in_sizes[0] / FD;
  const int E = in_sizes[1];

  char* ws = (char*)d_ws;
  size_t off = 0;
  auto alloc = [&](size_t bytes) -> void* {
    void* p = ws + off;
    off += (bytes + 255) & ~size_t(255);
    return p;
  };
  int* deg_out = (int*)alloc((size_t)N * 4);
  int* deg_in  = (int*)alloc((size_t)N * 4);
  int* row_ptr = (int*)alloc((size_t)(N + 1) * 4);
  int* bsum    = (int*)alloc(1024 * 4);
  int* boff    = (int*)alloc(1024 * 4);
  float* d_src = (float*)alloc((size_t)N * 4);
  float* d_dst = (float*)alloc((size_t)N * 4);
  int* erank   = (int*)alloc((size_t)E * 4);
  int* esrc    = (int*)alloc((size_t)E * 4);
  unsigned short* tb0  = (unsigned short*)alloc((size_t)N * FD * 2);
  unsigned short* tb1  = (unsigned short*)alloc((size_t)N * FD * 2);
  unsigned short* resb = (unsigned short*)alloc((size_t)N * FD * 2);

  hipMemsetAsync(deg_out, 0, (size_t)N * 4, stream);
  hipMemsetAsync(deg_in, 0, (size_t)N * 4, stream);

  int gE = (E + 255) / 256;
  int gN = (N + 255) / 256;
  int nb = gN;  // <= 1024

  k_degrank<<<gE, 256, 0, stream>>>(src, dst, deg_out, deg_in, erank, E);
  k_norm<<<gN, 256, 0, stream>>>(deg_out, deg_in, d_src, d_dst, N);
  k_bsum<<<nb, 256, 0, stream>>>(deg_in, bsum, N);
  k_bscan<<<1, 1024, 0, stream>>>(bsum, boff, nb);
  k_rowptr<<<nb, 256, 0, stream>>>(deg_in, boff, row_ptr, N, E);
  k_place<<<gE, 256, 0, stream>>>(src, dst, erank, row_ptr, esrc, E);

  dim3 g128((N + 63) / 64, 2);
  dim3 g64((N + 63) / 64, 1);
  int gA = (N + 3) / 4;
  const size_t LDS = 49152;

  // res = x @ Wr + br  (bf16 out)
  k_gemm<FD, false, false, true, true><<<g128, 256, LDS, stream>>>(x, Wr, br, nullptr, resb, N);
  // layer 1: h = d_src ⊙ (x @ W1)  (bf16 out)
  k_gemm<FD, false, true, false, true><<<g128, 256, LDS, stream>>>(x, W1, nullptr, d_src, tb0, N);
  k_agg<true, false><<<gA, 256, 0, stream>>>(tb0, row_ptr, esrc, d_dst, b1, nullptr, tb1, N);
  // layer 2
  k_gemm<FD, true, true, false, true><<<g128, 256, LDS, stream>>>(tb1, W2, nullptr, d_src, tb0, N);
  k_agg<true, false><<<gA, 256, 0, stream>>>(tb0, row_ptr, esrc, d_dst, b2, nullptr, tb1, N);
  // layer 3 + residual + relu
  k_gemm<FD, true, true, false, true><<<g128, 256, LDS, stream>>>(tb1, W3, nullptr, d_src, tb0, N);
  k_agg<true, true><<<gA, 256, 0, stream>>>(tb0, row_ptr, esrc, d_dst, b3, resb, tb1, N);
  // out = t1 @ Wo + bo  (fp32 out)
  k_gemm<CO, true, false, true, false><<<g64, 256, LDS, stream>>>(tb1, Wo, bo, nullptr, out, N);
}